// Round 1
// baseline (414.923 us; speedup 1.0000x reference)
//
#include <hip/hip_runtime.h>

#define B_ 64
#define T_ 512
#define F_ 1024
#define U_ 64

// ---------------------------------------------------------------------------
// Kernel 1: potentials[n][u] = x[n][:] . kernel[:][u] + bias[u] (+ boundaries)
// n = b*T + t, 32768 rows x 64 cols. Register-tiled VALU GEMM, no LDS:
// each thread owns 8 rows x 4 cols; x row reads are shared across the 16
// lanes with the same row-group via same-address coalescing; kernel matrix
// (256 KB) is L2-resident.
// ---------------------------------------------------------------------------
__global__ __launch_bounds__(256) void crf_gemm_kernel(
    const float* __restrict__ x, const float* __restrict__ w,
    const float* __restrict__ bias, const float* __restrict__ lb,
    const float* __restrict__ rb, float* __restrict__ pot)
{
    const int tid = threadIdx.x;
    const int rt = tid >> 4;        // 0..15 -> row group (8 rows)
    const int ut = tid & 15;        // 0..15 -> col group (4 cols)
    const int n0 = blockIdx.x * 128;
    const int r0 = rt * 8;
    const int u0 = ut * 4;

    float acc[8][4];
#pragma unroll
    for (int i = 0; i < 8; ++i)
#pragma unroll
        for (int j = 0; j < 4; ++j) acc[i][j] = 0.f;

    const float* xbase = x + (size_t)(n0 + r0) * F_;

    for (int f4 = 0; f4 < F_ / 4; ++f4) {
        float xv[8][4];
#pragma unroll
        for (int i = 0; i < 8; ++i) {
            const float4 t4 = *reinterpret_cast<const float4*>(
                xbase + (size_t)i * F_ + f4 * 4);
            xv[i][0] = t4.x; xv[i][1] = t4.y; xv[i][2] = t4.z; xv[i][3] = t4.w;
        }
        float kv[4][4];
#pragma unroll
        for (int ff = 0; ff < 4; ++ff) {
            const float4 t4 = *reinterpret_cast<const float4*>(
                w + (size_t)(f4 * 4 + ff) * U_ + u0);
            kv[ff][0] = t4.x; kv[ff][1] = t4.y; kv[ff][2] = t4.z; kv[ff][3] = t4.w;
        }
        // accumulate in ascending-f order (sequential f32 FMA)
#pragma unroll
        for (int ff = 0; ff < 4; ++ff)
#pragma unroll
            for (int i = 0; i < 8; ++i)
#pragma unroll
                for (int j = 0; j < 4; ++j)
                    acc[i][j] = fmaf(xv[i][ff], kv[ff][j], acc[i][j]);
    }

    // epilogue: + bias, then +left_boundary at t==0, +right_boundary at t==T-1
    const int t0 = n0 & (T_ - 1);   // n0 % 512 (128 | 512, so one b per block)
    const float4 bs4 = *reinterpret_cast<const float4*>(bias + u0);
    const float4 lb4 = *reinterpret_cast<const float4*>(lb + u0);
    const float4 rb4 = *reinterpret_cast<const float4*>(rb + u0);

#pragma unroll
    for (int i = 0; i < 8; ++i) {
        const int n = n0 + r0 + i;
        const int t = t0 + r0 + i;
        float4 o;
        o.x = acc[i][0] + bs4.x;
        o.y = acc[i][1] + bs4.y;
        o.z = acc[i][2] + bs4.z;
        o.w = acc[i][3] + bs4.w;
        if (t == 0)      { o.x += lb4.x; o.y += lb4.y; o.z += lb4.z; o.w += lb4.w; }
        if (t == T_ - 1) { o.x += rb4.x; o.y += rb4.y; o.z += rb4.z; o.w += rb4.w; }
        *reinterpret_cast<float4*>(pot + (size_t)n * U_ + u0) = o;
    }
}

// ---------------------------------------------------------------------------
// Kernel 2: Viterbi forward + backtrace, one block per batch element.
// 256 threads = 4 waves; thread (g, u) covers v in [g*16, g*16+16) for
// output tag u. Chain column held in registers; alpha broadcast from LDS;
// backpointers kept in LDS (u8) so backtrace is an LDS pointer chase.
// Arithmetic replicates the reference exactly:
//   s2 = (alpha[v] + chain[v][u]) + pot[t][u], strict-> max in ascending v
//   (first-occurrence argmax, matching jnp.argmax).
// ---------------------------------------------------------------------------
__global__ __launch_bounds__(256) void crf_viterbi_kernel(
    const float* __restrict__ pot, const float* __restrict__ chain,
    int* __restrict__ path)
{
    const int b = blockIdx.x;
    const int tid = threadIdx.x;
    const int u = tid & 63;
    const int g = tid >> 6;   // 0..3

    __shared__ __align__(16) float alpha_s[64];
    __shared__ float pval[4][64];
    __shared__ int   pidx[4][64];
    __shared__ unsigned char bp[T_ - 1][64];   // 32704 B

    float chain_r[16];
#pragma unroll
    for (int k = 0; k < 16; ++k)
        chain_r[k] = chain[(size_t)(g * 16 + k) * U_ + u];

    const float* potb = pot + (size_t)b * T_ * U_;

    if (g == 0) alpha_s[u] = potb[u];          // t = 0 row (bias+left included)
    __syncthreads();

    float pc = potb[(size_t)U_ + u];           // pot[t=1][u]

    for (int t = 1; t < T_; ++t) {
        // prefetch next pot row (hides L2 latency under the inner loop)
        const int tn = (t + 1 < T_) ? (t + 1) : (T_ - 1);
        const float pn = potb[(size_t)tn * U_ + u];

        const float4* a4 = reinterpret_cast<const float4*>(alpha_s);
        float best = -3.402823466e38f;
        int bidx = 0;
#pragma unroll
        for (int q = 0; q < 4; ++q) {
            const float4 av = a4[g * 4 + q];
            const float avv[4] = {av.x, av.y, av.z, av.w};
#pragma unroll
            for (int kk = 0; kk < 4; ++kk) {
                const int k = q * 4 + kk;
                const float s2 = (avv[kk] + chain_r[k]) + pc;
                if (s2 > best) { best = s2; bidx = g * 16 + k; }
            }
        }
        pval[g][u] = best;
        pidx[g][u] = bidx;
        __syncthreads();
        if (g == 0) {
            float bv = pval[0][u];
            int   bi = pidx[0][u];
#pragma unroll
            for (int j = 1; j < 4; ++j) {
                const float v = pval[j][u];
                if (v > bv) { bv = v; bi = pidx[j][u]; }   // strict >: lowest g wins ties
            }
            bp[t - 1][u] = (unsigned char)bi;
            alpha_s[u] = bv;
        }
        __syncthreads();
        pc = pn;
    }

    // final argmax (first occurrence) + backtrace, single thread per block
    if (tid == 0) {
        float bv = alpha_s[0];
        int bi = 0;
        for (int v = 1; v < 64; ++v) {
            const float a = alpha_s[v];
            if (a > bv) { bv = a; bi = v; }
        }
        int* pb = path + (size_t)b * T_;
        int tag = bi;
        pb[T_ - 1] = tag;
        for (int t = T_ - 2; t >= 0; --t) {
            tag = bp[t][tag];
            pb[t] = tag;
        }
    }
}

extern "C" void kernel_launch(void* const* d_in, const int* in_sizes, int n_in,
                              void* d_out, int out_size, void* d_ws, size_t ws_size,
                              hipStream_t stream) {
    const float* x  = (const float*)d_in[0];
    const float* w  = (const float*)d_in[1];
    const float* bs = (const float*)d_in[2];
    const float* ck = (const float*)d_in[3];
    const float* lb = (const float*)d_in[4];
    const float* rb = (const float*)d_in[5];

    float* pot = (float*)d_ws;          // [B*T][U] f32 = 8.39 MB
    int* path  = (int*)d_out;           // [B][T] int32

    crf_gemm_kernel<<<dim3(256), dim3(256), 0, stream>>>(x, w, bs, lb, rb, pot);
    crf_viterbi_kernel<<<dim3(B_), dim3(256), 0, stream>>>(pot, ck, path);
}